// Round 1
// baseline (115.233 us; speedup 1.0000x reference)
//
#include <hip/hip_runtime.h>
#include <hip/hip_bf16.h>
#include <stdint.h>

#define TOKENS 2048
#define DD 1024
#define HH 2048
#define NE 8
#define RP_CAP 3072   // padded-row capacity: 2048 + 8*127 rounded up
#define BM 128
#define BN 128
#define BK 64

typedef float f32x4 __attribute__((ext_vector_type(4)));
typedef short bf16x8 __attribute__((ext_vector_type(8)));
typedef unsigned int u32;

__device__ __forceinline__ unsigned short f2bf(float f) {
    union { float f; u32 u; } v; v.f = f;
    u32 u = v.u;
    return (unsigned short)((u + 0x7fffu + ((u >> 16) & 1u)) >> 16);
}

// ---------------- routing: expert per token, padded segments, perm ----------------
// ws header (ints): [0..8) cnt, [8..16) padded offsets, [16] total padded rows,
// [64..64+RP_CAP) perm (token id or -1)
__global__ __launch_bounds__(256) void k_route(const int* __restrict__ orig,
                                               const int* __restrict__ hmap,
                                               int* __restrict__ hdr) {
    __shared__ int s_e[TOKENS];
    __shared__ int s_cnt[NE];
    __shared__ int s_off[NE];
    int tid = threadIdx.x;
    if (tid < NE) s_cnt[tid] = 0;
    __syncthreads();
    for (int t = tid; t < TOKENS; t += 256) {
        int e = hmap[orig[t]];
        s_e[t] = e;
        atomicAdd(&s_cnt[e], 1);
    }
    __syncthreads();
    if (tid == 0) {
        int run = 0;
        for (int e = 0; e < NE; ++e) {
            s_off[e] = run;
            hdr[e] = s_cnt[e];
            hdr[8 + e] = run;
            run += ((s_cnt[e] + BM - 1) / BM) * BM;
        }
        hdr[16] = run;
    }
    __syncthreads();
    int* perm = hdr + 64;
    for (int r = tid; r < RP_CAP; r += 256) perm[r] = -1;
    if (tid < NE) s_cnt[tid] = 0;
    __syncthreads();
    for (int t = tid; t < TOKENS; t += 256) {
        int e = s_e[t];
        int pos = s_off[e] + atomicAdd(&s_cnt[e], 1);
        perm[pos] = t;
    }
}

// ---------------- gather x -> bf16 permuted padded layout ----------------
__global__ __launch_bounds__(256) void k_gather(const float* __restrict__ x,
                                                const int* __restrict__ hdr,
                                                unsigned short* __restrict__ xp) {
    int r = blockIdx.x;
    int t = hdr[64 + r];  // perm
    int tid = threadIdx.x;
    ushort4* dst = (ushort4*)(xp + (size_t)r * DD);
    if (t >= 0) {
        const float4* src = (const float4*)(x + (size_t)t * DD);
        float4 v = src[tid];
        ushort4 o;
        o.x = f2bf(v.x); o.y = f2bf(v.y); o.z = f2bf(v.z); o.w = f2bf(v.w);
        dst[tid] = o;
    } else {
        ushort4 z; z.x = 0; z.y = 0; z.z = 0; z.w = 0;
        dst[tid] = z;
    }
}

// ---------------- grouped GEMM: C = A(bf16,[RP][K]) * W(f32,[NE][N][K])^T ----------------
// A rows are expert-segmented (128-aligned). L1: +bias, relu, store bf16 h.
// L2: +bias, scatter rows to out[token] f32 via perm.
template<int KDIM, int NDIM, bool L2EPI>
__global__ __launch_bounds__(256) void k_gemm(const unsigned short* __restrict__ A,
                                              const float* __restrict__ W,
                                              const float* __restrict__ bias,
                                              const int* __restrict__ hdr,
                                              unsigned short* __restrict__ hout,
                                              float* __restrict__ out) {
    int total = hdr[16];
    int row0 = blockIdx.x * BM;
    if (row0 >= total) return;
    int e = 0;
#pragma unroll
    for (int i = 1; i < NE; ++i)
        if (row0 >= hdr[8 + i]) e = i;

    int n0 = blockIdx.y * BN;
    const float* We = W + (size_t)e * NDIM * KDIM;
    const float* be = bias + (size_t)e * NDIM;

    __shared__ __align__(16) unsigned short As[BM * BK];
    __shared__ __align__(16) unsigned short Bs[BN * BK];

    int tid = threadIdx.x;
    int w = tid >> 6, lane = tid & 63;
    int wr = w >> 1, wc = w & 1;
    int fr = lane & 15, hi = lane >> 4;

    f32x4 acc[4][4];
#pragma unroll
    for (int m = 0; m < 4; ++m)
#pragma unroll
        for (int n = 0; n < 4; ++n) acc[m][n] = f32x4{0.f, 0.f, 0.f, 0.f};

    for (int k0 = 0; k0 < KDIM; k0 += BK) {
        // ---- stage A via global_load_lds (linear LDS dest, pre-swizzled global source) ----
#pragma unroll
        for (int j = 0; j < 4; ++j) {
            int c16 = j * 256 + tid;        // 16B chunk id in [0,1024)
            int row = c16 >> 3;             // local row in tile
            int slot = c16 & 7;             // physical 16B slot within row
            int gslot = slot ^ (row & 7);   // inverse-swizzled source slot
            const unsigned short* gp = A + (size_t)(row0 + row) * KDIM + k0 + gslot * 8;
            unsigned short* lp = (unsigned short*)As + (size_t)(j * 4 + w) * 512;  // wave-uniform base
            __builtin_amdgcn_global_load_lds((const __attribute__((address_space(1))) u32*)gp,
                                             (__attribute__((address_space(3))) u32*)lp, 16, 0, 0);
        }
        // ---- stage B: f32 load -> bf16 -> swizzled ds_write_b128 ----
#pragma unroll
        for (int jr = 0; jr < 4; ++jr) {
            int c = jr * 256 + tid;         // 8-elem slot id in [0,1024)
            int row = c >> 3;
            int cl = c & 7;
            const float4* gp = (const float4*)(We + (size_t)(n0 + row) * KDIM + k0 + cl * 8);
            float4 v0 = gp[0];
            float4 v1 = gp[1];
            union { bf16x8 v; unsigned short s[8]; } o;
            o.s[0] = f2bf(v0.x); o.s[1] = f2bf(v0.y); o.s[2] = f2bf(v0.z); o.s[3] = f2bf(v0.w);
            o.s[4] = f2bf(v1.x); o.s[5] = f2bf(v1.y); o.s[6] = f2bf(v1.z); o.s[7] = f2bf(v1.w);
            int sp = cl ^ (row & 7);
            *(bf16x8*)&Bs[row * 64 + sp * 8] = o.v;
        }
        __syncthreads();

        // ---- fragments + MFMA ----
#pragma unroll
        for (int kk = 0; kk < BK; kk += 32) {
            bf16x8 af[4], bfr[4];
#pragma unroll
            for (int m = 0; m < 4; ++m) {
                int rr = wr * 64 + m * 16 + fr;
                int idx = (rr * 64 + kk + hi * 8) ^ ((rr & 7) << 3);
                af[m] = *(const bf16x8*)&As[idx];
            }
#pragma unroll
            for (int n = 0; n < 4; ++n) {
                int rn = wc * 64 + n * 16 + fr;
                int idx = (rn * 64 + kk + hi * 8) ^ ((rn & 7) << 3);
                bfr[n] = *(const bf16x8*)&Bs[idx];
            }
#pragma unroll
            for (int m = 0; m < 4; ++m)
#pragma unroll
                for (int n = 0; n < 4; ++n)
                    acc[m][n] = __builtin_amdgcn_mfma_f32_16x16x32_bf16(af[m], bfr[n], acc[m][n], 0, 0, 0);
        }
        __syncthreads();
    }

    // ---- epilogue ----
    const int* perm = hdr + 64;
    int rbase = row0 + wr * 64 + hi * 4;
    int cbase = n0 + wc * 64 + fr;
    if constexpr (!L2EPI) {
#pragma unroll
        for (int n = 0; n < 4; ++n) {
            int cg = cbase + n * 16;
            float bv = be[cg];
#pragma unroll
            for (int m = 0; m < 4; ++m) {
                int rg = rbase + m * 16;
#pragma unroll
                for (int r = 0; r < 4; ++r) {
                    float v = acc[m][n][r] + bv;
                    v = v > 0.f ? v : 0.f;
                    hout[(size_t)(rg + r) * NDIM + cg] = f2bf(v);
                }
            }
        }
    } else {
        float bv[4];
#pragma unroll
        for (int n = 0; n < 4; ++n) bv[n] = be[cbase + n * 16];
#pragma unroll
        for (int m = 0; m < 4; ++m) {
            int rg = rbase + m * 16;
#pragma unroll
            for (int r = 0; r < 4; ++r) {
                int t = perm[rg + r];
                if (t < 0) continue;
                float* op = out + (size_t)t * DD;
#pragma unroll
                for (int n = 0; n < 4; ++n)
                    op[cbase + n * 16] = acc[m][n][r] + bv[n];
            }
        }
    }
}

extern "C" void kernel_launch(void* const* d_in, const int* in_sizes, int n_in,
                              void* d_out, int out_size, void* d_ws, size_t ws_size,
                              hipStream_t stream) {
    const float* x    = (const float*)d_in[0];
    const int*   orig = (const int*)d_in[1];
    const int*   hmap = (const int*)d_in[2];
    const float* W1   = (const float*)d_in[3];
    const float* b1   = (const float*)d_in[4];
    const float* W2   = (const float*)d_in[5];
    const float* b2   = (const float*)d_in[6];
    float* out = (float*)d_out;

    int* hdr = (int*)d_ws;
    unsigned short* xp   = (unsigned short*)((char*)d_ws + 16384);
    unsigned short* hbuf = (unsigned short*)((char*)d_ws + 16384 + (size_t)RP_CAP * DD * 2);

    k_route<<<1, 256, 0, stream>>>(orig, hmap, hdr);
    k_gather<<<RP_CAP, 256, 0, stream>>>(x, hdr, xp);
    k_gemm<DD, HH, false><<<dim3(RP_CAP / BM, HH / BN), 256, 0, stream>>>(xp, W1, b1, hdr, hbuf, nullptr);
    k_gemm<HH, DD, true><<<dim3(RP_CAP / BM, DD / BN), 256, 0, stream>>>(hbuf, W2, b2, hdr, nullptr, out);
}

// Round 2
// 88.259 us; speedup vs baseline: 1.3056x; 1.3056x over previous
//
#include <hip/hip_runtime.h>
#include <hip/hip_bf16.h>
#include <stdint.h>

#define TOKENS 2048
#define DD 1024
#define HH 2048
#define NE 8
#define RP_CAP 3072   // padded-row capacity: 2048 + 8*127 rounded up
#define BM 128
#define BN 128
#define BK 64

typedef float f32x4 __attribute__((ext_vector_type(4)));
typedef short bf16x8 __attribute__((ext_vector_type(8)));
typedef unsigned int u32;

__device__ __forceinline__ unsigned short f2bf(float f) {
    union { float f; u32 u; } v; v.f = f;
    u32 u = v.u;
    return (unsigned short)((u + 0x7fffu + ((u >> 16) & 1u)) >> 16);
}

// ---------------- routing: expert per token, padded segments, perm ----------------
// ws header (ints): [0..8) cnt, [8..16) padded offsets, [16] total padded rows,
// [64..64+RP_CAP) perm (token id or -1)
__global__ __launch_bounds__(256) void k_route(const int* __restrict__ orig,
                                               const int* __restrict__ hmap,
                                               int* __restrict__ hdr) {
    __shared__ int s_e[TOKENS];
    __shared__ int s_cnt[NE];
    __shared__ int s_off[NE];
    int tid = threadIdx.x;
    if (tid < NE) s_cnt[tid] = 0;
    __syncthreads();
    for (int t = tid; t < TOKENS; t += 256) {
        int e = hmap[orig[t]];
        s_e[t] = e;
        atomicAdd(&s_cnt[e], 1);
    }
    __syncthreads();
    if (tid == 0) {
        int run = 0;
        for (int e = 0; e < NE; ++e) {
            s_off[e] = run;
            hdr[e] = s_cnt[e];
            hdr[8 + e] = run;
            run += ((s_cnt[e] + BM - 1) / BM) * BM;
        }
        hdr[16] = run;
    }
    __syncthreads();
    int* perm = hdr + 64;
    for (int r = tid; r < RP_CAP; r += 256) perm[r] = -1;
    if (tid < NE) s_cnt[tid] = 0;
    __syncthreads();
    for (int t = tid; t < TOKENS; t += 256) {
        int e = s_e[t];
        int pos = s_off[e] + atomicAdd(&s_cnt[e], 1);
        perm[pos] = t;
    }
}

// ---------------- gather x -> bf16 permuted padded layout ----------------
__global__ __launch_bounds__(256) void k_gather(const float* __restrict__ x,
                                                const int* __restrict__ hdr,
                                                unsigned short* __restrict__ xp) {
    int r = blockIdx.x;
    int t = hdr[64 + r];  // perm
    int tid = threadIdx.x;
    ushort4* dst = (ushort4*)(xp + (size_t)r * DD);
    if (t >= 0) {
        const float4* src = (const float4*)(x + (size_t)t * DD);
        float4 v = src[tid];
        ushort4 o;
        o.x = f2bf(v.x); o.y = f2bf(v.y); o.z = f2bf(v.z); o.w = f2bf(v.w);
        dst[tid] = o;
    } else {
        ushort4 z; z.x = 0; z.y = 0; z.z = 0; z.w = 0;
        dst[tid] = z;
    }
}

// ---------------- grouped GEMM: C = A(bf16,[RP][K]) * W(f32,[NE][N][K])^T ----------------
// 512 threads, 8 waves (2 rows x 4 cols of 64x32 sub-tiles), double-buffered LDS,
// 2-phase pipeline: issue next A (global_load_lds) + next B (f32->regs) BEFORE the
// current MFMA phase; convert+ds_write B after MFMA; one barrier per K-step.
// grid = (nblk, rowblk) so same-panel row-blocks land on the same XCD (idx % 8).
template<int KDIM, int NDIM, bool L2EPI>
__global__ __launch_bounds__(512, 2) void k_gemm(const unsigned short* __restrict__ A,
                                                 const float* __restrict__ W,
                                                 const float* __restrict__ bias,
                                                 const int* __restrict__ hdr,
                                                 unsigned short* __restrict__ hout,
                                                 float* __restrict__ out) {
    int total = hdr[16];
    int row0 = blockIdx.y * BM;
    if (row0 >= total) return;
    int e = 0;
#pragma unroll
    for (int i = 1; i < NE; ++i)
        if (row0 >= hdr[8 + i]) e = i;

    int n0 = blockIdx.x * BN;
    const float* We = W + (size_t)e * NDIM * KDIM;
    const float* be = bias + (size_t)e * NDIM;

    __shared__ __align__(16) unsigned short As[2 * BM * BK];
    __shared__ __align__(16) unsigned short Bs[2 * BN * BK];

    int tid = threadIdx.x;
    int w = tid >> 6, lane = tid & 63;
    int wr = w >> 2, wc = w & 3;          // wave grid 2 x 4
    int fr = lane & 15, hi = lane >> 4;

    f32x4 acc[4][2];
#pragma unroll
    for (int m = 0; m < 4; ++m)
#pragma unroll
        for (int n = 0; n < 2; ++n) acc[m][n] = f32x4{0.f, 0.f, 0.f, 0.f};

    float4 bv[4];

    auto STAGE_A = [&](int buf, int k0) {
#pragma unroll
        for (int j = 0; j < 2; ++j) {
            int c = j * 512 + tid;          // 16B chunk id in [0,1024)
            int row = c >> 3;
            int slot = c & 7;
            int gslot = slot ^ (row & 7);   // inverse-swizzled source slot
            const unsigned short* gp = A + (size_t)(row0 + row) * KDIM + k0 + gslot * 8;
            unsigned short* lp = (unsigned short*)As + buf * (BM * BK) + (j * 8 + w) * 512;
            __builtin_amdgcn_global_load_lds((const __attribute__((address_space(1))) u32*)gp,
                                             (__attribute__((address_space(3))) u32*)lp, 16, 0, 0);
        }
    };
    auto B_LOAD = [&](int k0) {
#pragma unroll
        for (int jr = 0; jr < 2; ++jr) {
            int c = jr * 512 + tid;
            int row = c >> 3;
            int cl = c & 7;
            const float4* gp = (const float4*)(We + (size_t)(n0 + row) * KDIM + k0 + cl * 8);
            bv[jr * 2]     = gp[0];
            bv[jr * 2 + 1] = gp[1];
        }
    };
    auto B_WRITE = [&](int buf) {
        unsigned short* Bb = Bs + buf * (BN * BK);
#pragma unroll
        for (int jr = 0; jr < 2; ++jr) {
            int c = jr * 512 + tid;
            int row = c >> 3;
            int cl = c & 7;
            float4 v0 = bv[jr * 2], v1 = bv[jr * 2 + 1];
            union { bf16x8 v; unsigned short s[8]; } o;
            o.s[0] = f2bf(v0.x); o.s[1] = f2bf(v0.y); o.s[2] = f2bf(v0.z); o.s[3] = f2bf(v0.w);
            o.s[4] = f2bf(v1.x); o.s[5] = f2bf(v1.y); o.s[6] = f2bf(v1.z); o.s[7] = f2bf(v1.w);
            int sp = cl ^ (row & 7);
            *(bf16x8*)&Bb[row * 64 + sp * 8] = o.v;
        }
    };

    constexpr int NT = KDIM / BK;

    // prologue: fill buf 0
    STAGE_A(0, 0);
    B_LOAD(0);
    B_WRITE(0);
    __syncthreads();

    for (int t = 0; t < NT; ++t) {
        int cur = t & 1;
        bool pf = (t + 1 < NT);
        if (pf) {
            STAGE_A(cur ^ 1, (t + 1) * BK);   // async into other LDS buf
            B_LOAD((t + 1) * BK);             // f32 weights into regs, in flight
        }
        const unsigned short* Ab = As + cur * (BM * BK);
        const unsigned short* Bb = Bs + cur * (BN * BK);
#pragma unroll
        for (int kk = 0; kk < BK; kk += 32) {
            bf16x8 af[4], bfr[2];
#pragma unroll
            for (int m = 0; m < 4; ++m) {
                int rr = wr * 64 + m * 16 + fr;
                int idx = (rr * 64 + kk + hi * 8) ^ ((rr & 7) << 3);
                af[m] = *(const bf16x8*)&Ab[idx];
            }
#pragma unroll
            for (int n = 0; n < 2; ++n) {
                int cn = wc * 32 + n * 16 + fr;
                int idx = (cn * 64 + kk + hi * 8) ^ ((cn & 7) << 3);
                bfr[n] = *(const bf16x8*)&Bb[idx];
            }
#pragma unroll
            for (int m = 0; m < 4; ++m)
#pragma unroll
                for (int n = 0; n < 2; ++n)
                    acc[m][n] = __builtin_amdgcn_mfma_f32_16x16x32_bf16(af[m], bfr[n], acc[m][n], 0, 0, 0);
        }
        if (pf) B_WRITE(cur ^ 1);   // first use of bv -> compiler's vmcnt wait lands here
        __syncthreads();            // drains gload_lds (vmcnt) + ds_writes (lgkmcnt)
    }

    // ---- epilogue ----
    const int* perm = hdr + 64;
    int rbase = row0 + wr * 64 + hi * 4;
    int cbase = n0 + wc * 32 + fr;
    if constexpr (!L2EPI) {
#pragma unroll
        for (int n = 0; n < 2; ++n) {
            int cg = cbase + n * 16;
            float bvv = be[cg];
#pragma unroll
            for (int m = 0; m < 4; ++m) {
                int rg = rbase + m * 16;
#pragma unroll
                for (int r = 0; r < 4; ++r) {
                    float v = acc[m][n][r] + bvv;
                    v = v > 0.f ? v : 0.f;
                    hout[(size_t)(rg + r) * NDIM + cg] = f2bf(v);
                }
            }
        }
    } else {
        float bvv[2];
#pragma unroll
        for (int n = 0; n < 2; ++n) bvv[n] = be[cbase + n * 16];
#pragma unroll
        for (int m = 0; m < 4; ++m) {
            int rg = rbase + m * 16;
#pragma unroll
            for (int r = 0; r < 4; ++r) {
                int t = perm[rg + r];
                if (t < 0) continue;
                float* op = out + (size_t)t * DD;
#pragma unroll
                for (int n = 0; n < 2; ++n)
                    op[cbase + n * 16] = acc[m][n][r] + bvv[n];
            }
        }
    }
}

extern "C" void kernel_launch(void* const* d_in, const int* in_sizes, int n_in,
                              void* d_out, int out_size, void* d_ws, size_t ws_size,
                              hipStream_t stream) {
    const float* x    = (const float*)d_in[0];
    const int*   orig = (const int*)d_in[1];
    const int*   hmap = (const int*)d_in[2];
    const float* W1   = (const float*)d_in[3];
    const float* b1   = (const float*)d_in[4];
    const float* W2   = (const float*)d_in[5];
    const float* b2   = (const float*)d_in[6];
    float* out = (float*)d_out;

    int* hdr = (int*)d_ws;
    unsigned short* xp   = (unsigned short*)((char*)d_ws + 16384);
    unsigned short* hbuf = (unsigned short*)((char*)d_ws + 16384 + (size_t)RP_CAP * DD * 2);

    k_route<<<1, 256, 0, stream>>>(orig, hmap, hdr);
    k_gather<<<RP_CAP, 256, 0, stream>>>(x, hdr, xp);
    // grid = (n-blocks, row-blocks): same-weight-panel row-blocks share an XCD (idx%8)
    k_gemm<DD, HH, false><<<dim3(HH / BN, RP_CAP / BM), 512, 0, stream>>>(xp, W1, b1, hdr, hbuf, nullptr);
    k_gemm<HH, DD, true><<<dim3(DD / BN, RP_CAP / BM), 512, 0, stream>>>(hbuf, W2, b2, hdr, nullptr, out);
}

// Round 3
// 86.625 us; speedup vs baseline: 1.3302x; 1.0189x over previous
//
#include <hip/hip_runtime.h>
#include <hip/hip_bf16.h>
#include <stdint.h>

#define TOKENS 2048
#define DD 1024
#define HH 2048
#define NE 8
#define RP_CAP 3072   // padded-row capacity: 2048 + 8*127 rounded up
#define BM 128
#define BN 128
#define BK 64

typedef float f32x4 __attribute__((ext_vector_type(4)));
typedef short bf16x8 __attribute__((ext_vector_type(8)));
typedef unsigned int u32;

__device__ __forceinline__ unsigned short f2bf(float f) {
    union { float f; u32 u; } v; v.f = f;
    u32 u = v.u;
    return (unsigned short)((u + 0x7fffu + ((u >> 16) & 1u)) >> 16);
}

// ---------------- routing: expert per token, padded segments, perm ----------------
__global__ __launch_bounds__(256) void k_route(const int* __restrict__ orig,
                                               const int* __restrict__ hmap,
                                               int* __restrict__ hdr) {
    __shared__ int s_e[TOKENS];
    __shared__ int s_cnt[NE];
    __shared__ int s_off[NE];
    int tid = threadIdx.x;
    if (tid < NE) s_cnt[tid] = 0;
    __syncthreads();
    for (int t = tid; t < TOKENS; t += 256) {
        int e = hmap[orig[t]];
        s_e[t] = e;
        atomicAdd(&s_cnt[e], 1);
    }
    __syncthreads();
    if (tid == 0) {
        int run = 0;
        for (int e = 0; e < NE; ++e) {
            s_off[e] = run;
            hdr[e] = s_cnt[e];
            hdr[8 + e] = run;
            run += ((s_cnt[e] + BM - 1) / BM) * BM;
        }
        hdr[16] = run;
    }
    __syncthreads();
    int* perm = hdr + 64;
    for (int r = tid; r < RP_CAP; r += 256) perm[r] = -1;
    if (tid < NE) s_cnt[tid] = 0;
    __syncthreads();
    for (int t = tid; t < TOKENS; t += 256) {
        int e = s_e[t];
        int pos = s_off[e] + atomicAdd(&s_cnt[e], 1);
        perm[pos] = t;
    }
}

// ---------------- gather x -> bf16 permuted padded layout ----------------
__global__ __launch_bounds__(256) void k_gather(const float* __restrict__ x,
                                                const int* __restrict__ hdr,
                                                unsigned short* __restrict__ xp) {
    int r = blockIdx.x;
    int t = hdr[64 + r];  // perm
    int tid = threadIdx.x;
    ushort4* dst = (ushort4*)(xp + (size_t)r * DD);
    if (t >= 0) {
        const float4* src = (const float4*)(x + (size_t)t * DD);
        float4 v = src[tid];
        ushort4 o;
        o.x = f2bf(v.x); o.y = f2bf(v.y); o.z = f2bf(v.z); o.w = f2bf(v.w);
        dst[tid] = o;
    } else {
        ushort4 z; z.x = 0; z.y = 0; z.z = 0; z.w = 0;
        dst[tid] = z;
    }
}

// ---------------- grouped GEMM: C = A(bf16,[RP][K]) * W(f32,[NE][N][K])^T ----------------
// 512 threads, 8 waves (2M x 4N of 64x32 sub-tiles), double-buffered LDS + double-
// buffered B reg stage. Counted-vmcnt raw-barrier pipeline (T4): per K-step,
// s_waitcnt vmcnt(4) lgkmcnt(0) + s_barrier keeps the 4 next-next B loads in
// flight across the barrier; only the last steps drain to 0.
template<int KDIM, int NDIM, bool L2EPI>
__global__ __launch_bounds__(512, 2) void k_gemm(const unsigned short* __restrict__ A,
                                                 const float* __restrict__ W,
                                                 const float* __restrict__ bias,
                                                 const int* __restrict__ hdr,
                                                 unsigned short* __restrict__ hout,
                                                 float* __restrict__ out) {
    int total = hdr[16];
    int row0 = blockIdx.y * BM;
    if (row0 >= total) return;
    int e = 0;
#pragma unroll
    for (int i = 1; i < NE; ++i)
        if (row0 >= hdr[8 + i]) e = i;

    int n0 = blockIdx.x * BN;
    const float* We = W + (size_t)e * NDIM * KDIM;
    const float* be = bias + (size_t)e * NDIM;

    __shared__ __align__(16) unsigned short As[2 * BM * BK];
    __shared__ __align__(16) unsigned short Bs[2 * BN * BK];

    int tid = threadIdx.x;
    int w = tid >> 6, lane = tid & 63;
    int wr = w >> 2, wc = w & 3;          // wave grid 2 x 4
    int fr = lane & 15, hi = lane >> 4;

    f32x4 acc[4][2];
#pragma unroll
    for (int m = 0; m < 4; ++m)
#pragma unroll
        for (int n = 0; n < 2; ++n) acc[m][n] = f32x4{0.f, 0.f, 0.f, 0.f};

    float4 bvA[4], bvB[4];   // two named reg-stage sets (compile-time indexed)

    auto STAGE_A = [&](int buf, int k0) {
#pragma unroll
        for (int j = 0; j < 2; ++j) {
            int c = j * 512 + tid;          // 16B chunk id in [0,1024)
            int row = c >> 3;
            int slot = c & 7;
            int gslot = slot ^ (row & 7);   // inverse-swizzled source slot
            const unsigned short* gp = A + (size_t)(row0 + row) * KDIM + k0 + gslot * 8;
            unsigned short* lp = (unsigned short*)As + buf * (BM * BK) + (j * 8 + w) * 512;
            __builtin_amdgcn_global_load_lds((const __attribute__((address_space(1))) u32*)gp,
                                             (__attribute__((address_space(3))) u32*)lp, 16, 0, 0);
        }
    };
    auto B_LOAD = [&](float4 (&bv)[4], int k0) {
#pragma unroll
        for (int jr = 0; jr < 2; ++jr) {
            int c = jr * 512 + tid;
            int row = c >> 3;
            int cl = c & 7;
            const float4* gp = (const float4*)(We + (size_t)(n0 + row) * KDIM + k0 + cl * 8);
            bv[jr * 2]     = gp[0];
            bv[jr * 2 + 1] = gp[1];
        }
    };
    auto B_WRITE = [&](const float4 (&bv)[4], int buf) {
        unsigned short* Bb = Bs + buf * (BN * BK);
#pragma unroll
        for (int jr = 0; jr < 2; ++jr) {
            int c = jr * 512 + tid;
            int row = c >> 3;
            int cl = c & 7;
            float4 v0 = bv[jr * 2], v1 = bv[jr * 2 + 1];
            union { bf16x8 v; unsigned short s[8]; } o;
            o.s[0] = f2bf(v0.x); o.s[1] = f2bf(v0.y); o.s[2] = f2bf(v0.z); o.s[3] = f2bf(v0.w);
            o.s[4] = f2bf(v1.x); o.s[5] = f2bf(v1.y); o.s[6] = f2bf(v1.z); o.s[7] = f2bf(v1.w);
            int sp = cl ^ (row & 7);
            *(bf16x8*)&Bb[row * 64 + sp * 8] = o.v;
        }
    };
    auto COMPUTE = [&](int buf) {
        const unsigned short* Ab = As + buf * (BM * BK);
        const unsigned short* Bb = Bs + buf * (BN * BK);
#pragma unroll
        for (int kk = 0; kk < BK; kk += 32) {
            bf16x8 af[4], bfr[2];
#pragma unroll
            for (int m = 0; m < 4; ++m) {
                int rr = wr * 64 + m * 16 + fr;
                int idx = (rr * 64 + kk + hi * 8) ^ ((rr & 7) << 3);
                af[m] = *(const bf16x8*)&Ab[idx];
            }
#pragma unroll
            for (int n = 0; n < 2; ++n) {
                int cn = wc * 32 + n * 16 + fr;
                int idx = (cn * 64 + kk + hi * 8) ^ ((cn & 7) << 3);
                bfr[n] = *(const bf16x8*)&Bb[idx];
            }
#pragma unroll
            for (int m = 0; m < 4; ++m)
#pragma unroll
                for (int n = 0; n < 2; ++n)
                    acc[m][n] = __builtin_amdgcn_mfma_f32_16x16x32_bf16(af[m], bfr[n], acc[m][n], 0, 0, 0);
        }
    };

    constexpr int NT = KDIM / BK;   // 16 or 32 (even)

#define WAIT_KEEP4 asm volatile("s_waitcnt vmcnt(4) lgkmcnt(0)" ::: "memory")
#define WAIT_ALL   asm volatile("s_waitcnt vmcnt(0) lgkmcnt(0)" ::: "memory")
#define BARRIER    do { __builtin_amdgcn_s_barrier(); asm volatile("" ::: "memory"); } while (0)

    // prologue: tile0 -> LDS buf0; tile1 -> bvB (stays in regs)
    STAGE_A(0, 0);
    B_LOAD(bvA, 0);
    B_LOAD(bvB, BK);
    B_WRITE(bvA, 0);          // compiler waits vmcnt(4): bvA ready, bvB still in flight
    WAIT_KEEP4;               // A staged; bvB loads remain outstanding
    BARRIER;

    for (int t = 0; t < NT; t += 2) {
        // ---- even step: compute bufs 0, stage tile t+1 into bufs 1 ----
        STAGE_A(1, (t + 1) * BK);
        if (t + 2 < NT) B_LOAD(bvA, (t + 2) * BK);
        COMPUTE(0);
        B_WRITE(bvB, 1);      // tile t+1 -> Bs1 (compiler vmcnt(6) covers bvB)
        if (t + 2 < NT) WAIT_KEEP4; else WAIT_ALL;
        BARRIER;
        // ---- odd step: compute bufs 1, stage tile t+2 into bufs 0 ----
        if (t + 2 < NT) {
            STAGE_A(0, (t + 2) * BK);
            if (t + 3 < NT) B_LOAD(bvB, (t + 3) * BK);
            COMPUTE(1);
            B_WRITE(bvA, 0);  // tile t+2 -> Bs0
            if (t + 3 < NT) WAIT_KEEP4; else WAIT_ALL;
            BARRIER;
        } else {
            COMPUTE(1);       // last tile; no staging, fall through to epilogue
        }
    }
#undef WAIT_KEEP4
#undef WAIT_ALL
#undef BARRIER

    // ---- epilogue ----
    const int* perm = hdr + 64;
    int rbase = row0 + wr * 64 + hi * 4;
    int cbase = n0 + wc * 32 + fr;
    if constexpr (!L2EPI) {
#pragma unroll
        for (int n = 0; n < 2; ++n) {
            int cg = cbase + n * 16;
            float bvv = be[cg];
#pragma unroll
            for (int m = 0; m < 4; ++m) {
                int rg = rbase + m * 16;
#pragma unroll
                for (int r = 0; r < 4; ++r) {
                    float v = acc[m][n][r] + bvv;
                    v = v > 0.f ? v : 0.f;
                    hout[(size_t)(rg + r) * NDIM + cg] = f2bf(v);
                }
            }
        }
    } else {
        float bvv[2];
#pragma unroll
        for (int n = 0; n < 2; ++n) bvv[n] = be[cbase + n * 16];
#pragma unroll
        for (int m = 0; m < 4; ++m) {
            int rg = rbase + m * 16;
#pragma unroll
            for (int r = 0; r < 4; ++r) {
                int t = perm[rg + r];
                if (t < 0) continue;
                float* op = out + (size_t)t * DD;
#pragma unroll
                for (int n = 0; n < 2; ++n)
                    op[cbase + n * 16] = acc[m][n][r] + bvv[n];
            }
        }
    }
}

extern "C" void kernel_launch(void* const* d_in, const int* in_sizes, int n_in,
                              void* d_out, int out_size, void* d_ws, size_t ws_size,
                              hipStream_t stream) {
    const float* x    = (const float*)d_in[0];
    const int*   orig = (const int*)d_in[1];
    const int*   hmap = (const int*)d_in[2];
    const float* W1   = (const float*)d_in[3];
    const float* b1   = (const float*)d_in[4];
    const float* W2   = (const float*)d_in[5];
    const float* b2   = (const float*)d_in[6];
    float* out = (float*)d_out;

    int* hdr = (int*)d_ws;
    unsigned short* xp   = (unsigned short*)((char*)d_ws + 16384);
    unsigned short* hbuf = (unsigned short*)((char*)d_ws + 16384 + (size_t)RP_CAP * DD * 2);

    k_route<<<1, 256, 0, stream>>>(orig, hmap, hdr);
    k_gather<<<RP_CAP, 256, 0, stream>>>(x, hdr, xp);
    // grid = (n-blocks, row-blocks): same-weight-panel row-blocks share an XCD (idx%8)
    k_gemm<DD, HH, false><<<dim3(HH / BN, RP_CAP / BM), 512, 0, stream>>>(xp, W1, b1, hdr, hbuf, nullptr);
    k_gemm<HH, DD, true><<<dim3(DD / BN, RP_CAP / BM), 512, 0, stream>>>(hbuf, W2, b2, hdr, nullptr, out);
}

// Round 4
// 78.346 us; speedup vs baseline: 1.4708x; 1.1057x over previous
//
#include <hip/hip_runtime.h>
#include <hip/hip_bf16.h>
#include <stdint.h>

#define TOKENS 2048
#define DD 1024
#define HH 2048
#define NE 8
#define RP_CAP 3072   // padded-row capacity: 2048 + 8*127 rounded up
#define BM 128
#define BN 64
#define BK 64

typedef float f32x4 __attribute__((ext_vector_type(4)));
typedef short bf16x8 __attribute__((ext_vector_type(8)));
typedef unsigned int u32;

__device__ __forceinline__ unsigned short f2bf(float f) {
    union { float f; u32 u; } v; v.f = f;
    u32 u = v.u;
    return (unsigned short)((u + 0x7fffu + ((u >> 16) & 1u)) >> 16);
}

// ---------------- routing: expert per token, padded segments, perm ----------------
__global__ __launch_bounds__(256) void k_route(const int* __restrict__ orig,
                                               const int* __restrict__ hmap,
                                               int* __restrict__ hdr) {
    __shared__ int s_e[TOKENS];
    __shared__ int s_cnt[NE];
    __shared__ int s_off[NE];
    int tid = threadIdx.x;
    if (tid < NE) s_cnt[tid] = 0;
    __syncthreads();
    for (int t = tid; t < TOKENS; t += 256) {
        int e = hmap[orig[t]];
        s_e[t] = e;
        atomicAdd(&s_cnt[e], 1);
    }
    __syncthreads();
    if (tid == 0) {
        int run = 0;
        for (int e = 0; e < NE; ++e) {
            s_off[e] = run;
            hdr[e] = s_cnt[e];
            hdr[8 + e] = run;
            run += ((s_cnt[e] + BM - 1) / BM) * BM;
        }
        hdr[16] = run;
    }
    __syncthreads();
    int* perm = hdr + 64;
    for (int r = tid; r < RP_CAP; r += 256) perm[r] = -1;
    if (tid < NE) s_cnt[tid] = 0;
    __syncthreads();
    for (int t = tid; t < TOKENS; t += 256) {
        int e = s_e[t];
        int pos = s_off[e] + atomicAdd(&s_cnt[e], 1);
        perm[pos] = t;
    }
}

// ---------------- gather x -> bf16 permuted padded layout ----------------
__global__ __launch_bounds__(256) void k_gather(const float* __restrict__ x,
                                                const int* __restrict__ hdr,
                                                unsigned short* __restrict__ xp) {
    int r = blockIdx.x;
    int t = hdr[64 + r];  // perm
    int tid = threadIdx.x;
    ushort4* dst = (ushort4*)(xp + (size_t)r * DD);
    if (t >= 0) {
        const float4* src = (const float4*)(x + (size_t)t * DD);
        float4 v = src[tid];
        ushort4 o;
        o.x = f2bf(v.x); o.y = f2bf(v.y); o.z = f2bf(v.z); o.w = f2bf(v.w);
        dst[tid] = o;
    } else {
        ushort4 z; z.x = 0; z.y = 0; z.z = 0; z.w = 0;
        dst[tid] = z;
    }
}

// ---------------- grouped GEMM: C = A(bf16,[RP][K]) * W(f32,[NE][N][K])^T ----------------
// 256 threads, 4 waves (2M x 2N of 64x32 sub-tiles), tile 128x64, BK=64.
// Double-buffered LDS (48 KB total -> 3 blocks/CU) + double-buffered B reg stage.
// Counted-vmcnt raw-barrier pipeline: end-of-step s_waitcnt vmcnt(4) drains this
// step's 4 A global_load_lds while keeping the 4 next-next B loads in flight.
template<int KDIM, int NDIM, bool L2EPI>
__global__ __launch_bounds__(256, 3) void k_gemm(const unsigned short* __restrict__ A,
                                                 const float* __restrict__ W,
                                                 const float* __restrict__ bias,
                                                 const int* __restrict__ hdr,
                                                 unsigned short* __restrict__ hout,
                                                 float* __restrict__ out) {
    int total = hdr[16];
    int row0 = blockIdx.y * BM;
    if (row0 >= total) return;
    int e = 0;
#pragma unroll
    for (int i = 1; i < NE; ++i)
        if (row0 >= hdr[8 + i]) e = i;

    int n0 = blockIdx.x * BN;
    const float* We = W + (size_t)e * NDIM * KDIM;
    const float* be = bias + (size_t)e * NDIM;

    __shared__ __align__(16) unsigned short As[2 * BM * BK];   // 2 x 16 KB
    __shared__ __align__(16) unsigned short Bs[2 * BN * BK];   // 2 x 8 KB

    int tid = threadIdx.x;
    int w = tid >> 6, lane = tid & 63;
    int wr = w >> 1, wc = w & 1;          // wave grid 2M x 2N
    int fr = lane & 15, hi = lane >> 4;

    f32x4 acc[4][2];
#pragma unroll
    for (int m = 0; m < 4; ++m)
#pragma unroll
        for (int n = 0; n < 2; ++n) acc[m][n] = f32x4{0.f, 0.f, 0.f, 0.f};

    float4 bvA[4], bvB[4];   // two named reg-stage sets (compile-time indexed)

    auto STAGE_A = [&](int buf, int k0) {
#pragma unroll
        for (int j = 0; j < 4; ++j) {
            int c = j * 256 + tid;          // 16B chunk id in [0,1024)
            int row = c >> 3;               // [0,128)
            int slot = c & 7;
            int gslot = slot ^ (row & 7);   // inverse-swizzled source slot
            const unsigned short* gp = A + (size_t)(row0 + row) * KDIM + k0 + gslot * 8;
            unsigned short* lp = (unsigned short*)As + buf * (BM * BK) + j * 2048 + w * 512;
            __builtin_amdgcn_global_load_lds((const __attribute__((address_space(1))) u32*)gp,
                                             (__attribute__((address_space(3))) u32*)lp, 16, 0, 0);
        }
    };
    auto B_LOAD = [&](float4 (&bv)[4], int k0) {
#pragma unroll
        for (int jr = 0; jr < 2; ++jr) {
            int c = jr * 256 + tid;         // 8-f32 group id in [0,512)
            int row = c >> 3;               // [0,64)
            int cl = c & 7;
            const float4* gp = (const float4*)(We + (size_t)(n0 + row) * KDIM + k0 + cl * 8);
            bv[jr * 2]     = gp[0];
            bv[jr * 2 + 1] = gp[1];
        }
    };
    auto B_WRITE = [&](const float4 (&bv)[4], int buf) {
        unsigned short* Bb = Bs + buf * (BN * BK);
#pragma unroll
        for (int jr = 0; jr < 2; ++jr) {
            int c = jr * 256 + tid;
            int row = c >> 3;
            int cl = c & 7;
            float4 v0 = bv[jr * 2], v1 = bv[jr * 2 + 1];
            union { bf16x8 v; unsigned short s[8]; } o;
            o.s[0] = f2bf(v0.x); o.s[1] = f2bf(v0.y); o.s[2] = f2bf(v0.z); o.s[3] = f2bf(v0.w);
            o.s[4] = f2bf(v1.x); o.s[5] = f2bf(v1.y); o.s[6] = f2bf(v1.z); o.s[7] = f2bf(v1.w);
            int sp = cl ^ (row & 7);
            *(bf16x8*)&Bb[row * 64 + sp * 8] = o.v;
        }
    };
    auto COMPUTE = [&](int buf) {
        const unsigned short* Ab = As + buf * (BM * BK);
        const unsigned short* Bb = Bs + buf * (BN * BK);
#pragma unroll
        for (int kk = 0; kk < BK; kk += 32) {
            bf16x8 af[4], bfr[2];
#pragma unroll
            for (int m = 0; m < 4; ++m) {
                int rr = wr * 64 + m * 16 + fr;
                int idx = (rr * 64 + kk + hi * 8) ^ ((rr & 7) << 3);
                af[m] = *(const bf16x8*)&Ab[idx];
            }
#pragma unroll
            for (int n = 0; n < 2; ++n) {
                int cn = wc * 32 + n * 16 + fr;
                int idx = (cn * 64 + kk + hi * 8) ^ ((cn & 7) << 3);
                bfr[n] = *(const bf16x8*)&Bb[idx];
            }
#pragma unroll
            for (int m = 0; m < 4; ++m)
#pragma unroll
                for (int n = 0; n < 2; ++n)
                    acc[m][n] = __builtin_amdgcn_mfma_f32_16x16x32_bf16(af[m], bfr[n], acc[m][n], 0, 0, 0);
        }
    };

    constexpr int NT = KDIM / BK;   // 16 or 32 (even)

#define WAIT_KEEP4 asm volatile("s_waitcnt vmcnt(4) lgkmcnt(0)" ::: "memory")
#define WAIT_ALL   asm volatile("s_waitcnt vmcnt(0) lgkmcnt(0)" ::: "memory")
#define BARRIER    do { __builtin_amdgcn_s_barrier(); asm volatile("" ::: "memory"); } while (0)

    // prologue: tile0 -> LDS buf0; tile1's B -> bvB (stays in regs)
    STAGE_A(0, 0);
    B_LOAD(bvA, 0);
    B_LOAD(bvB, BK);
    B_WRITE(bvA, 0);          // compiler waits vmcnt(4): bvA ready, bvB still in flight
    WAIT_KEEP4;               // A staged; bvB loads remain outstanding
    BARRIER;

    for (int t = 0; t < NT; t += 2) {
        // ---- even step: compute buf 0, stage tile t+1 into buf 1 ----
        STAGE_A(1, (t + 1) * BK);
        if (t + 2 < NT) B_LOAD(bvA, (t + 2) * BK);
        COMPUTE(0);
        B_WRITE(bvB, 1);      // tile t+1 -> Bs1 (compiler vmcnt wait covers bvB)
        if (t + 2 < NT) WAIT_KEEP4; else WAIT_ALL;
        BARRIER;
        // ---- odd step: compute buf 1, stage tile t+2 into buf 0 ----
        if (t + 2 < NT) {
            STAGE_A(0, (t + 2) * BK);
            if (t + 3 < NT) B_LOAD(bvB, (t + 3) * BK);
            COMPUTE(1);
            B_WRITE(bvA, 0);  // tile t+2 -> Bs0
            if (t + 3 < NT) WAIT_KEEP4; else WAIT_ALL;
            BARRIER;
        } else {
            COMPUTE(1);       // last tile; no staging, fall through to epilogue
        }
    }
#undef WAIT_KEEP4
#undef WAIT_ALL
#undef BARRIER

    // ---- epilogue ----
    const int* perm = hdr + 64;
    int rbase = row0 + wr * 64 + hi * 4;
    int cbase = n0 + wc * 32 + fr;
    if constexpr (!L2EPI) {
#pragma unroll
        for (int n = 0; n < 2; ++n) {
            int cg = cbase + n * 16;
            float bvv = be[cg];
#pragma unroll
            for (int m = 0; m < 4; ++m) {
                int rg = rbase + m * 16;
#pragma unroll
                for (int r = 0; r < 4; ++r) {
                    float v = acc[m][n][r] + bvv;
                    v = v > 0.f ? v : 0.f;
                    hout[(size_t)(rg + r) * NDIM + cg] = f2bf(v);
                }
            }
        }
    } else {
        float bvv[2];
#pragma unroll
        for (int n = 0; n < 2; ++n) bvv[n] = be[cbase + n * 16];
#pragma unroll
        for (int m = 0; m < 4; ++m) {
            int rg = rbase + m * 16;
#pragma unroll
            for (int r = 0; r < 4; ++r) {
                int t = perm[rg + r];
                if (t < 0) continue;
                float* op = out + (size_t)t * DD;
#pragma unroll
                for (int n = 0; n < 2; ++n)
                    op[cbase + n * 16] = acc[m][n][r] + bvv[n];
            }
        }
    }
}

extern "C" void kernel_launch(void* const* d_in, const int* in_sizes, int n_in,
                              void* d_out, int out_size, void* d_ws, size_t ws_size,
                              hipStream_t stream) {
    const float* x    = (const float*)d_in[0];
    const int*   orig = (const int*)d_in[1];
    const int*   hmap = (const int*)d_in[2];
    const float* W1   = (const float*)d_in[3];
    const float* b1   = (const float*)d_in[4];
    const float* W2   = (const float*)d_in[5];
    const float* b2   = (const float*)d_in[6];
    float* out = (float*)d_out;

    int* hdr = (int*)d_ws;
    unsigned short* xp   = (unsigned short*)((char*)d_ws + 16384);
    unsigned short* hbuf = (unsigned short*)((char*)d_ws + 16384 + (size_t)RP_CAP * DD * 2);

    k_route<<<1, 256, 0, stream>>>(orig, hmap, hdr);
    k_gather<<<RP_CAP, 256, 0, stream>>>(x, hdr, xp);
    // grid = (n-blocks, row-blocks): same-weight-panel row-blocks share an XCD (idx%8)
    k_gemm<DD, HH, false><<<dim3(HH / BN, RP_CAP / BM), 256, 0, stream>>>(xp, W1, b1, hdr, hbuf, nullptr);
    k_gemm<HH, DD, true><<<dim3(DD / BN, RP_CAP / BM), 256, 0, stream>>>(hbuf, W2, b2, hdr, nullptr, out);
}